// Round 2
// baseline (209.919 us; speedup 1.0000x reference)
//
#include <hip/hip_runtime.h>
#include <hip/hip_bf16.h>

// STDP: delta_w[q,p] = 4*w*(1-w) * (A/B) * sum_k AT[q][k]*BT[p][k]
//   AT[q][ b*128+t        ] = post_spikes[b][t][q]
//   AT[q][ 2048 + b*128+t ] = post_trace [b][t][q]
//   BT[p][ b*128+t        ] = pre_trace  [b][t][p]
//   BT[p][ 2048 + b*128+t ] = -pre_spikes[b][t][p]

typedef __attribute__((ext_vector_type(8))) short bf16x8;
typedef __attribute__((ext_vector_type(4))) float f32x4;

#define GN 2048
#define GK 4096
#define A_SCALE (0.01f / 16.0f)

#define GLOAD_LDS16(gp, lp) \
    __builtin_amdgcn_global_load_lds((const __attribute__((address_space(1))) void*)(gp), \
                                     (__attribute__((address_space(3))) void*)(lp), 16, 0, 0)

// ---------------------------------------------------------------------------
// zero d_out (16 MB) before the atomic split-K GEMM. grid 4096 x 256.
// ---------------------------------------------------------------------------
__global__ __launch_bounds__(256) void zero_out(float4* __restrict__ out)
{
    out[(size_t)blockIdx.x * 256 + threadIdx.x] = float4{0.f, 0.f, 0.f, 0.f};
}

// ---------------------------------------------------------------------------
// Kernel 1: trace + transpose, LDS-cooperative.
// grid (32, 16, 2) = 1024 blocks, block 256 (4 waves). z=0: post->AT, z=1: pre->BT
// Each block: 64-n slab x one b x one tensor.
//   phase 1: coop-load 64n x 128t fp32 slab -> LDS (stride-65 pad), also bf16 spikes
//   phase 2: wave w scans t-prefix from LDS, keeps its 32-t trace segment in regs
//   phase 3: trace bf16 -> LDS (overlay on fp32 buf)
//   phase 4: coalesced 16B-chunk writes of both halves of AT/BT rows
// LDS 49.9 KB -> 3 blocks/CU = 12 waves/CU.
// ---------------------------------------------------------------------------
__global__ __launch_bounds__(256) void trace_kernel(
    const float* __restrict__ pre,
    const float* __restrict__ post,
    const int* __restrict__ dtp,
    __hip_bfloat16* __restrict__ AT,
    __hip_bfloat16* __restrict__ BT)
{
    __shared__ char smem[128 * 65 * 4 + 128 * 65 * 2];  // 49920 B
    float* fbuf = (float*)smem;                                     // [128][65] fp32
    __hip_bfloat16* spk = (__hip_bfloat16*)(smem + 128 * 65 * 4);   // [128][65] bf16
    __hip_bfloat16* trb = (__hip_bfloat16*)smem;                    // [128][65] overlay

    const int tid = threadIdx.x;
    const int w   = tid >> 6;    // wave 0..3
    const int l   = tid & 63;
    const int n0  = blockIdx.x * 64;
    const int b   = blockIdx.y;
    const int a   = blockIdx.z;

    int di = dtp[0];
    float dtf = (di > 0 && di < 1000000) ? (float)di : *(const float*)dtp;
    const float decay = __expf(-dtf / 20.0f);

    const float* src = (a == 0) ? post : pre;
    const float  sgn = (a == 0) ? 1.0f : -1.0f;  // BT spikes carry the minus sign

    // phase 1: cooperative load. t = i*4 + w, n = n0 + l. 256B/wave-inst, 32 indep loads.
    #pragma unroll 8
    for (int i = 0; i < 32; ++i) {
        const int t = i * 4 + w;
        float v = src[((size_t)b * 128 + t) * GN + n0 + l];
        fbuf[t * 65 + l] = v;
        spk[t * 65 + l]  = __float2bfloat16(v * sgn);
    }
    __syncthreads();

    // phase 2: scan. trace[0]=0; trace[t] = decay*trace[t-1] + s[t] (t>=1).
    const int t0 = 32 * w;
    float carry = 0.0f;
    #pragma unroll 8
    for (int t = 1; t < t0; ++t)
        carry = decay * carry + fbuf[t * 65 + l];
    float seg[32];
    #pragma unroll
    for (int j = 0; j < 32; ++j) {
        const int t = t0 + j;
        if (t >= 1) carry = decay * carry + fbuf[t * 65 + l];
        seg[j] = carry;  // t=0 -> 0
    }
    __syncthreads();   // all waves done reading fbuf

    // phase 3: trace bf16 into overlay
    #pragma unroll
    for (int j = 0; j < 32; ++j)
        trb[(t0 + j) * 65 + l] = __float2bfloat16(seg[j]);
    __syncthreads();

    // phase 4: write out. 2048 16B-chunks/block, 8 per thread, lane-consecutive.
    const __hip_bfloat16* s1 = (a == 0) ? spk : trb;  // first k-half
    const __hip_bfloat16* s2 = (a == 0) ? trb : spk;  // second k-half
    __hip_bfloat16* dst = (a == 0) ? AT : BT;

    #pragma unroll
    for (int j = 0; j < 8; ++j) {
        const int c   = tid + 256 * j;
        const int n   = c >> 5;          // 0..63
        const int sec = (c >> 4) & 1;    // 0: first half, 1: second half
        const int tc  = c & 15;          // 16B chunk within 128 t
        const __hip_bfloat16* s = sec ? s2 : s1;
        unsigned int vv[8];
        #pragma unroll
        for (int i = 0; i < 8; ++i)
            vv[i] = *(const unsigned short*)&s[(8 * tc + i) * 65 + n];
        uint4 pk;
        pk.x = vv[0] | (vv[1] << 16);
        pk.y = vv[2] | (vv[3] << 16);
        pk.z = vv[4] | (vv[5] << 16);
        pk.w = vv[6] | (vv[7] << 16);
        const size_t off = (size_t)(n0 + n) * GK + (sec ? (2048 + b * 128) : (b * 128)) + tc * 8;
        *(uint4*)(dst + off) = pk;
    }
}

// ---------------------------------------------------------------------------
// Kernel 2: split-K GEMM. C = AT * BT^T, K split 4 ways -> grid (16,16,4),
// 4 blocks/CU (LDS 32KB x4 = 128KB), 16 waves/CU. Partial results scaled by
// the w-factor epilogue and atomicAdd-ed into pre-zeroed d_out.
// 128x128 tile, BK=64, mfma 16x16x32 bf16, global_load_lds(16B) staging,
// XOR k-chunk swizzle applied on the SOURCE pointer (LDS dest is lane-forced).
// ---------------------------------------------------------------------------
__global__ __launch_bounds__(256) void stdp_gemm(
    const __hip_bfloat16* __restrict__ AT,
    const __hip_bfloat16* __restrict__ BT,
    const float* __restrict__ W,
    float* __restrict__ out)
{
    __shared__ alignas(16) __hip_bfloat16 As[128 * 64];
    __shared__ alignas(16) __hip_bfloat16 Bs[128 * 64];

    const int tid  = threadIdx.x;
    const int lane = tid & 63;
    const int wv   = tid >> 6;          // wave 0..3
    const int wm   = (wv >> 1) * 64;
    const int wn   = (wv & 1) * 64;
    const int RM   = blockIdx.y * 128;  // q base
    const int CN   = blockIdx.x * 128;  // p base
    const int KZ   = blockIdx.z * 1024; // k-slice base
    const int l15  = lane & 15;
    const int quad = lane >> 4;

    f32x4 acc[4][4] = {};

    for (int k0 = KZ; k0 < KZ + 1024; k0 += 64) {
        __syncthreads();
        #pragma unroll
        for (int it = 0; it < 4; ++it) {
            const int cbase = it * 256 + wv * 64;
            const int c     = cbase + lane;
            const int row   = c >> 3;
            const int kc    = (c & 7) ^ (row & 7);
            const __hip_bfloat16* ga = AT + (size_t)(RM + row) * GK + k0 + kc * 8;
            const __hip_bfloat16* gb = BT + (size_t)(CN + row) * GK + k0 + kc * 8;
            GLOAD_LDS16(ga, As + (size_t)cbase * 8);
            GLOAD_LDS16(gb, Bs + (size_t)cbase * 8);
        }
        __syncthreads();

        #pragma unroll
        for (int kk = 0; kk < 64; kk += 32) {
            const int jg = (kk >> 3) + quad;
            bf16x8 af[4], bfr[4];
            #pragma unroll
            for (int i = 0; i < 4; ++i) {
                const int mr = wm + i * 16 + l15;
                af[i]  = *(const bf16x8*)(As + mr * 64 + ((jg ^ (mr & 7)) * 8));
                const int nr = wn + i * 16 + l15;
                bfr[i] = *(const bf16x8*)(Bs + nr * 64 + ((jg ^ (nr & 7)) * 8));
            }
            #pragma unroll
            for (int i = 0; i < 4; ++i)
                #pragma unroll
                for (int j = 0; j < 4; ++j)
                    acc[i][j] = __builtin_amdgcn_mfma_f32_16x16x32_bf16(
                        af[i], bfr[j], acc[i][j], 0, 0, 0);
        }
    }

    // epilogue: C/D layout col = lane&15, row = quad*4 + reg (m89-verified).
    // Fused softbound factor; split-K partials summed via device-scope atomicAdd.
    #pragma unroll
    for (int i = 0; i < 4; ++i) {
        #pragma unroll
        for (int r = 0; r < 4; ++r) {
            const int q = RM + wm + i * 16 + quad * 4 + r;
            #pragma unroll
            for (int j = 0; j < 4; ++j) {
                const int p = CN + wn + j * 16 + l15;
                const float w  = W[(size_t)q * GN + p];
                const float wf = 4.0f * w * (1.0f - w);
                atomicAdd(&out[(size_t)q * GN + p], wf * A_SCALE * acc[i][j][r]);
            }
        }
    }
}

extern "C" void kernel_launch(void* const* d_in, const int* in_sizes, int n_in,
                              void* d_out, int out_size, void* d_ws, size_t ws_size,
                              hipStream_t stream) {
    const float* W    = (const float*)d_in[0];  // [2048][2048]
    const float* pre  = (const float*)d_in[1];  // [16][128][2048]
    const float* post = (const float*)d_in[2];  // [16][128][2048]
    const int*   dt   = (const int*)d_in[3];
    float* out = (float*)d_out;

    __hip_bfloat16* AT = (__hip_bfloat16*)d_ws;            // 16 MB
    __hip_bfloat16* BT = AT + (size_t)GN * GK;             // +16 MB

    zero_out<<<4096, 256, 0, stream>>>((float4*)out);
    trace_kernel<<<dim3(32, 16, 2), 256, 0, stream>>>(pre, post, dt, AT, BT);
    stdp_gemm<<<dim3(16, 16, 4), 256, 0, stream>>>(AT, BT, W, out);
}

// Round 3
// 171.067 us; speedup vs baseline: 1.2271x; 1.2271x over previous
//
#include <hip/hip_runtime.h>
#include <hip/hip_bf16.h>

// STDP: delta_w[q,p] = 4*w*(1-w) * (A/B) * sum_k AT[q][k]*BT[p][k]
//   AT[q][ b*128+t        ] = post_spikes[b][t][q]
//   AT[q][ 2048 + b*128+t ] = post_trace [b][t][q]
//   BT[p][ b*128+t        ] = pre_trace  [b][t][p]
//   BT[p][ 2048 + b*128+t ] = -pre_spikes[b][t][p]

typedef __attribute__((ext_vector_type(8))) short bf16x8;
typedef __attribute__((ext_vector_type(4))) float f32x4;

#define GN 2048
#define GK 4096
#define A_SCALE (0.01f / 16.0f)

#define GLOAD_LDS16(gp, lp) \
    __builtin_amdgcn_global_load_lds((const __attribute__((address_space(1))) void*)(gp), \
                                     (__attribute__((address_space(3))) void*)(lp), 16, 0, 0)

// ---------------------------------------------------------------------------
// Kernel 1: trace + transpose, LDS-cooperative (unchanged from R2 - ~17us).
// grid (32, 16, 2), block 256 (4 waves). z=0: post->AT, z=1: pre->BT
// ---------------------------------------------------------------------------
__global__ __launch_bounds__(256) void trace_kernel(
    const float* __restrict__ pre,
    const float* __restrict__ post,
    const int* __restrict__ dtp,
    __hip_bfloat16* __restrict__ AT,
    __hip_bfloat16* __restrict__ BT)
{
    __shared__ char smem[128 * 65 * 4 + 128 * 65 * 2];  // 49920 B -> 3 blocks/CU
    float* fbuf = (float*)smem;                                     // [128][65] fp32
    __hip_bfloat16* spk = (__hip_bfloat16*)(smem + 128 * 65 * 4);   // [128][65] bf16
    __hip_bfloat16* trb = (__hip_bfloat16*)smem;                    // [128][65] overlay

    const int tid = threadIdx.x;
    const int w   = tid >> 6;    // wave 0..3
    const int l   = tid & 63;
    const int n0  = blockIdx.x * 64;
    const int b   = blockIdx.y;
    const int a   = blockIdx.z;

    int di = dtp[0];
    float dtf = (di > 0 && di < 1000000) ? (float)di : *(const float*)dtp;
    const float decay = __expf(-dtf / 20.0f);

    const float* src = (a == 0) ? post : pre;
    const float  sgn = (a == 0) ? 1.0f : -1.0f;  // BT spikes carry the minus sign

    // phase 1: cooperative load. t = i*4 + w, n = n0 + l.
    #pragma unroll 8
    for (int i = 0; i < 32; ++i) {
        const int t = i * 4 + w;
        float v = src[((size_t)b * 128 + t) * GN + n0 + l];
        fbuf[t * 65 + l] = v;
        spk[t * 65 + l]  = __float2bfloat16(v * sgn);
    }
    __syncthreads();

    // phase 2: scan. trace[0]=0; trace[t] = decay*trace[t-1] + s[t] (t>=1).
    const int t0 = 32 * w;
    float carry = 0.0f;
    #pragma unroll 8
    for (int t = 1; t < t0; ++t)
        carry = decay * carry + fbuf[t * 65 + l];
    float seg[32];
    #pragma unroll
    for (int j = 0; j < 32; ++j) {
        const int t = t0 + j;
        if (t >= 1) carry = decay * carry + fbuf[t * 65 + l];
        seg[j] = carry;  // t=0 -> 0
    }
    __syncthreads();   // all waves done reading fbuf

    // phase 3: trace bf16 into overlay
    #pragma unroll
    for (int j = 0; j < 32; ++j)
        trb[(t0 + j) * 65 + l] = __float2bfloat16(seg[j]);
    __syncthreads();

    // phase 4: 2048 16B-chunks/block, 8 per thread, lane-consecutive.
    const __hip_bfloat16* s1 = (a == 0) ? spk : trb;  // first k-half
    const __hip_bfloat16* s2 = (a == 0) ? trb : spk;  // second k-half
    __hip_bfloat16* dst = (a == 0) ? AT : BT;

    #pragma unroll
    for (int j = 0; j < 8; ++j) {
        const int c   = tid + 256 * j;
        const int n   = c >> 5;          // 0..63
        const int sec = (c >> 4) & 1;    // 0: first half, 1: second half
        const int tc  = c & 15;          // 16B chunk within 128 t
        const __hip_bfloat16* s = sec ? s2 : s1;
        unsigned int vv[8];
        #pragma unroll
        for (int i = 0; i < 8; ++i)
            vv[i] = *(const unsigned short*)&s[(8 * tc + i) * 65 + n];
        uint4 pk;
        pk.x = vv[0] | (vv[1] << 16);
        pk.y = vv[2] | (vv[3] << 16);
        pk.z = vv[4] | (vv[5] << 16);
        pk.w = vv[6] | (vv[7] << 16);
        const size_t off = (size_t)(n0 + n) * GK + (sec ? (2048 + b * 128) : (b * 128)) + tc * 8;
        *(uint4*)(dst + off) = pk;
    }
}

// ---------------------------------------------------------------------------
// Kernel 2: C = AT * BT^T, 128x128 tile, BK=64, DOUBLE-BUFFERED LDS staging.
// grid (16,16) = 256 blocks = 1 block/CU, 4 waves of 64x64.
// Per iter: barrier (drains PREVIOUS iter's loads - already complete after a
// full compute phase) -> issue async loads into other buffer -> compute.
// This hides the global_load_lds latency that R1 exposed at 1 wave/SIMD.
// LDS 64 KB. XOR k-chunk swizzle on the SOURCE pointer (LDS dest lane-forced).
// ---------------------------------------------------------------------------
__global__ __launch_bounds__(256) void stdp_gemm(
    const __hip_bfloat16* __restrict__ AT,
    const __hip_bfloat16* __restrict__ BT,
    const float* __restrict__ W,
    float* __restrict__ out)
{
    __shared__ alignas(16) __hip_bfloat16 As[2][128 * 64];
    __shared__ alignas(16) __hip_bfloat16 Bs[2][128 * 64];

    const int tid  = threadIdx.x;
    const int lane = tid & 63;
    const int wv   = tid >> 6;          // wave 0..3
    const int wm   = (wv >> 1) * 64;
    const int wn   = (wv & 1) * 64;
    const int RM   = blockIdx.y * 128;  // q base
    const int CN   = blockIdx.x * 128;  // p base
    const int l15  = lane & 15;
    const int quad = lane >> 4;

    f32x4 acc[4][4] = {};

    // precomputed per-lane staging offsets (row/kc depend only on lane+it+wv)
    auto stage = [&](int buf, int k0) {
        #pragma unroll
        for (int it = 0; it < 4; ++it) {
            const int cbase = it * 256 + wv * 64;      // wave-uniform chunk base
            const int c     = cbase + lane;
            const int row   = c >> 3;
            const int kc    = (c & 7) ^ (row & 7);     // XOR swizzle (self-inverse)
            const __hip_bfloat16* ga = AT + (size_t)(RM + row) * GK + k0 + kc * 8;
            const __hip_bfloat16* gb = BT + (size_t)(CN + row) * GK + k0 + kc * 8;
            GLOAD_LDS16(ga, &As[buf][cbase * 8]);
            GLOAD_LDS16(gb, &Bs[buf][cbase * 8]);
        }
    };

    auto compute = [&](int buf) {
        #pragma unroll
        for (int kk = 0; kk < 64; kk += 32) {
            const int jg = (kk >> 3) + quad;
            bf16x8 af[4], bfr[4];
            #pragma unroll
            for (int i = 0; i < 4; ++i) {
                const int mr = wm + i * 16 + l15;
                af[i]  = *(const bf16x8*)(&As[buf][mr * 64 + ((jg ^ (mr & 7)) * 8)]);
                const int nr = wn + i * 16 + l15;
                bfr[i] = *(const bf16x8*)(&Bs[buf][nr * 64 + ((jg ^ (nr & 7)) * 8)]);
            }
            #pragma unroll
            for (int i = 0; i < 4; ++i)
                #pragma unroll
                for (int j = 0; j < 4; ++j)
                    acc[i][j] = __builtin_amdgcn_mfma_f32_16x16x32_bf16(
                        af[i], bfr[j], acc[i][j], 0, 0, 0);
        }
    };

    stage(0, 0);
    #pragma unroll 2
    for (int t = 1; t < 64; ++t) {
        __syncthreads();               // drains loads issued LAST iter (cheap now)
        stage(t & 1, t * 64);          // async loads into the other buffer
        compute((t - 1) & 1);          // MFMA on the buffer staged last iter
    }
    __syncthreads();
    compute(1);                        // tile 63 lives in buf 1

    // epilogue: C/D layout col = lane&15, row = quad*4 + reg (m89-verified)
    #pragma unroll
    for (int i = 0; i < 4; ++i) {
        #pragma unroll
        for (int r = 0; r < 4; ++r) {
            const int q = RM + wm + i * 16 + quad * 4 + r;
            #pragma unroll
            for (int j = 0; j < 4; ++j) {
                const int p = CN + wn + j * 16 + l15;
                const float w  = W[(size_t)q * GN + p];
                const float wf = 4.0f * w * (1.0f - w);
                out[(size_t)q * GN + p] = wf * A_SCALE * acc[i][j][r];
            }
        }
    }
}

extern "C" void kernel_launch(void* const* d_in, const int* in_sizes, int n_in,
                              void* d_out, int out_size, void* d_ws, size_t ws_size,
                              hipStream_t stream) {
    const float* W    = (const float*)d_in[0];  // [2048][2048]
    const float* pre  = (const float*)d_in[1];  // [16][128][2048]
    const float* post = (const float*)d_in[2];  // [16][128][2048]
    const int*   dt   = (const int*)d_in[3];
    float* out = (float*)d_out;

    __hip_bfloat16* AT = (__hip_bfloat16*)d_ws;            // 16 MB
    __hip_bfloat16* BT = AT + (size_t)GN * GK;             // +16 MB

    trace_kernel<<<dim3(32, 16, 2), 256, 0, stream>>>(pre, post, dt, AT, BT);
    stdp_gemm<<<dim3(16, 16), 256, 0, stream>>>(AT, BT, W, out);
}